// Round 2
// baseline (426.663 us; speedup 1.0000x reference)
//
#include <hip/hip_runtime.h>

// SNN forward scan (LIF, Heaviside forward). T=2048, B=64, F=512.
// W is block-diagonal with 2x2 blocks -> per feature pair (f0,f0+1) the
// synapse is a 2x2 matvec; all other dot terms are exact fp32 zeros, so this
// is bitwise identical to the reference's full dot product.
//
// R8: R7's producer/consumer split fixed read-side MLP (4 producer waves,
// 32 KB in flight/CU) but left ALL stores on the single compute wave:
// 8 B/lane nt stores through one wave's ~8-entry vmem queue = ~4 KB store
// traffic in flight/CU -> ~2.7 TB/s write ceiling, below the 6.3 TB/s
// fair-share the roofline needs. Fix: stage output through LDS too.
//   - compute wave: ds_write_b64 spikes into a double-buffered out-LDS
//     region (no global stores at all -> shorter serial chain).
//   - producer waves: one iteration later, ds_read_b128 the staged chunk
//     and issue 16 B/lane dwordx4 nt stores (4 waves x 8 KB = 32 KB store
//     in flight/CU, matching the read side, 2x wider per instruction).
// LDS = 2x32 KiB (x, double-buffered) + 2x32 KiB (out) = 128 KiB; fits the
// 160 KiB/CU budget at the intentional 1 block/CU. All LDS accesses are
// <=2-way bank aliasing (free). Compute arithmetic is instruction-identical
// to the passing R7 kernel -> bitwise-identical output.

typedef float v2f __attribute__((ext_vector_type(2)));
typedef float v4f __attribute__((ext_vector_type(4)));

constexpr int T_STEPS = 2048;
constexpr int B_DIM   = 64;
constexpr int F_DIM   = 512;
constexpr int BF      = B_DIM * F_DIM;          // 32768 floats per timestep
constexpr int BLK_FLOATS = 128;                 // floats per block per step (64 pairs)
constexpr int NBLK    = BF / BLK_FLOATS;        // 256 blocks (1 per CU)
constexpr int CHUNK   = 64;                     // timesteps per LDS buffer
constexpr int NCHUNK  = T_STEPS / CHUNK;        // 32
constexpr int NPROD   = 4;                      // producer waves per block
constexpr int STEPS_PER_PROD = CHUNK / NPROD;   // 16 steps per producer wave
constexpr int LOADS_PER_PROD = STEPS_PER_PROD / 2; // 8 dwordx4 insts (2 steps each)
constexpr int BUF_FLOATS = CHUNK * BLK_FLOATS;  // 8192 floats = 32 KiB per buffer

__global__ __launch_bounds__(320, 1) void snn_scan_kernel(
    const float* __restrict__ x,
    const float* __restrict__ W,
    const float* __restrict__ leak_i,
    const float* __restrict__ leak_v,
    const float* __restrict__ thresh,
    float* __restrict__ out) {

    __shared__ __attribute__((aligned(16))) float lds_x[2][BUF_FLOATS];  // 64 KiB
    __shared__ __attribute__((aligned(16))) float lds_o[2][BUF_FLOATS];  // 64 KiB

    const int tid  = threadIdx.x;
    const int wid  = tid >> 6;
    const int lane = tid & 63;
    const int blk  = blockIdx.x;
    const bool is_prod = (wid < NPROD);

    // ---------------- producer setup (waves 0..3) ----------------
    // One dwordx4 instruction covers 2 timesteps: lanes 0-31 -> step s
    // (contiguous 512 B slice of this block), lanes 32-63 -> step s+1.
    const int  half = lane >> 5;                 // 0 or 1
    const int  l32  = lane & 31;
    const int  sbase = wid * STEPS_PER_PROD + half;  // this lane's first step in chunk
    const float* xsrc = x   + (size_t)blk * BLK_FLOATS + (size_t)l32 * 4;
    float*       odst = out + (size_t)blk * BLK_FLOATS + (size_t)l32 * 4;

    // ---------------- compute setup (wave 4) ----------------
    const int e  = blk * BLK_FLOATS + lane * 2;  // flat b*F + f0 (even)
    const int f0 = e & (F_DIM - 1);
    float w00 = 0.f, w01 = 0.f, w10 = 0.f, w11 = 0.f;
    float li0 = 0.f, li1 = 0.f, lv0 = 0.f, lv1 = 0.f, th0 = 0.f, th1 = 0.f;
    if (!is_prod) {
        w00 = W[(size_t)(f0    ) * F_DIM + f0    ];
        w01 = W[(size_t)(f0    ) * F_DIM + f0 + 1];
        w10 = W[(size_t)(f0 + 1) * F_DIM + f0    ];
        w11 = W[(size_t)(f0 + 1) * F_DIM + f0 + 1];
        li0 = leak_i[f0]; li1 = leak_i[f0 + 1];
        lv0 = leak_v[f0]; lv1 = leak_v[f0 + 1];
        th0 = thresh[f0]; th1 = thresh[f0 + 1];
    }
    float i0 = 0.f, v0 = 0.f, z0 = 0.f;   // even-f neuron state
    float i1 = 0.f, v1 = 0.f, z1 = 0.f;   // odd-f neuron state

    // Stage x chunk c into lds_x[c&1]. Issue all 8 loads (8 KB in flight per
    // producer wave), then the LDS writes.
    auto produce = [&](int c) {
        const int db = c & 1;
        const float* gb = xsrc + (size_t)(c * CHUNK + sbase) * BF;
        v4f r[LOADS_PER_PROD];
        #pragma unroll
        for (int i = 0; i < LOADS_PER_PROD; ++i)
            r[i] = __builtin_nontemporal_load(
                       (const v4f*)(gb + (size_t)(2 * i) * BF));
        float* lb = &lds_x[db][(size_t)sbase * BLK_FLOATS + (size_t)l32 * 4];
        #pragma unroll
        for (int i = 0; i < LOADS_PER_PROD; ++i)
            *(v4f*)(lb + (size_t)(2 * i) * BLK_FLOATS) = r[i];
    };

    // Drain out chunk c from lds_o[c&1] to global: 16 B/lane dwordx4 nt
    // stores, fire-and-forget (8 KB store traffic in flight per producer).
    auto store_out = [&](int c) {
        const int db = c & 1;
        const float* lb = &lds_o[db][(size_t)sbase * BLK_FLOATS + (size_t)l32 * 4];
        float* gb = odst + (size_t)(c * CHUNK + sbase) * BF;
        v4f r[LOADS_PER_PROD];
        #pragma unroll
        for (int i = 0; i < LOADS_PER_PROD; ++i)
            r[i] = *(const v4f*)(lb + (size_t)(2 * i) * BLK_FLOATS);
        #pragma unroll
        for (int i = 0; i < LOADS_PER_PROD; ++i)
            __builtin_nontemporal_store(r[i], (v4f*)(gb + (size_t)(2 * i) * BF));
    };

    // Serial recurrence over chunk c: LDS in, LDS out. No global traffic.
    auto consume = [&](int c) {
        const int db = c & 1;
        const float* lb = &lds_x[db][(size_t)lane * 2];
        float*       lo = &lds_o[db][(size_t)lane * 2];
        #pragma unroll 8
        for (int j = 0; j < CHUNK; ++j) {
            const v2f xv = *(const v2f*)(lb + (size_t)j * BLK_FLOATS);
            const float xe = xv.x;
            const float xo = xv.y;
            // ff = 2x2 block matvec; remaining dot terms are exact zeros.
            const float ff0 = __fadd_rn(__fmul_rn(w00, xe), __fmul_rn(w01, xo));
            const float ff1 = __fadd_rn(__fmul_rn(w10, xe), __fmul_rn(w11, xo));
            // i_new = leak_i*i + ff
            i0 = __fadd_rn(__fmul_rn(li0, i0), ff0);
            i1 = __fadd_rn(__fmul_rn(li1, i1), ff1);
            // v_new = (leak_v*v)*(1-z) + i_new ; z in {0,1} -> select
            float vm0 = __fmul_rn(lv0, v0);
            float vm1 = __fmul_rn(lv1, v1);
            vm0 = (z0 > 0.0f) ? 0.0f : vm0;
            vm1 = (z1 > 0.0f) ? 0.0f : vm1;
            v0 = __fadd_rn(vm0, i0);
            v1 = __fadd_rn(vm1, i1);
            // z_new = heaviside(v_new - thresh) == (v_new > thresh)
            z0 = (v0 > th0) ? 1.0f : 0.0f;
            z1 = (v1 > th1) ? 1.0f : 0.0f;
            v2f zv; zv.x = z0; zv.y = z1;
            *(v2f*)(lo + (size_t)j * BLK_FLOATS) = zv;
        }
    };

    // Pipeline (all barriers in uniform control flow):
    //   iter c: producers load x chunk c+1 and drain out chunk c-1;
    //           compute wave runs chunk c into lds_o[c&1].
    // Buffer checks: producers read lds_o[(c-1)&1] while compute writes
    // lds_o[c&1] (distinct); compute overwrites lds_o[c&1] two iterations
    // after it was drained (separated by a barrier).
    if (is_prod) produce(0);
    __syncthreads();

    for (int c = 0; c < NCHUNK; ++c) {
        if (is_prod) {
            if (c + 1 < NCHUNK) produce(c + 1);
            if (c > 0) store_out(c - 1);
        } else {
            consume(c);
        }
        __syncthreads();
    }
    // Epilogue: drain the final chunk (staged by compute in the last iter).
    if (is_prod) store_out(NCHUNK - 1);
}

extern "C" void kernel_launch(void* const* d_in, const int* in_sizes, int n_in,
                              void* d_out, int out_size, void* d_ws, size_t ws_size,
                              hipStream_t stream) {
    const float* x      = (const float*)d_in[0];
    const float* W      = (const float*)d_in[1];
    const float* leak_i = (const float*)d_in[2];
    const float* leak_v = (const float*)d_in[3];
    const float* thresh = (const float*)d_in[4];
    float* out = (float*)d_out;

    // 256 blocks x 320 threads: 4 producer waves + 1 compute wave per CU.
    snn_scan_kernel<<<dim3(NBLK), dim3(320), 0, stream>>>(
        x, W, leak_i, leak_v, thresh, out);
}